// Round 9
// baseline (1045.741 us; speedup 1.0000x reference)
//
#include <hip/hip_runtime.h>
#include <math.h>

#define BB 2
#define SS 1024
#define HH 768
#define NHEAD 12
#define HDIM 64
#define NLAYER 4
#define VV 32000
#define MROWS (BB*SS)

typedef unsigned short u16;
typedef __attribute__((ext_vector_type(8))) short short8;
typedef __attribute__((ext_vector_type(4))) float f32x4;
typedef __attribute__((ext_vector_type(4))) unsigned short u16x4;

__device__ __forceinline__ u16 f2bf(float f) {
    union { float f; unsigned u; } x; x.f = f;
    unsigned r = (x.u + 0x7fff + ((x.u >> 16) & 1)) >> 16;
    return (u16)r;
}
__device__ __forceinline__ float bf2f(u16 b) {
    union { unsigned u; float f; } x; x.u = ((unsigned)b) << 16;
    return x.f;
}

__device__ __forceinline__ void gload_lds16(const u16* g, u16* l) {
    __builtin_amdgcn_global_load_lds((const __attribute__((address_space(1))) void*)g,
                                     (__attribute__((address_space(3))) void*)l, 16, 0, 0);
}

// ---------------- weight convert + transpose: W[K][N] f32 -> Wt[N][K] bf16 ----
__global__ __launch_bounds__(256) void conv_transpose(
    const float* __restrict__ W, u16* __restrict__ Wt, int K, int N) {
    int l = blockIdx.z;
    W  += (size_t)l * K * N;
    Wt += (size_t)l * K * N;
    __shared__ u16 tile[32][33];        // tile[n][k]
    int k0 = blockIdx.y * 32, n0 = blockIdx.x * 32;
    int t = threadIdx.x;                // 256
    int ky = t >> 3, nx = (t & 7) * 4;  // load: row k0+ky, cols n0+nx..+3
    float4 v = *(const float4*)(W + (size_t)(k0 + ky) * N + n0 + nx);
    tile[nx + 0][ky] = f2bf(v.x);
    tile[nx + 1][ky] = f2bf(v.y);
    tile[nx + 2][ky] = f2bf(v.z);
    tile[nx + 3][ky] = f2bf(v.w);
    __syncthreads();
    int nr = t >> 3, kc = (t & 7) * 4;  // store: row n0+nr, cols k0+kc..+3
    u16x4 o;
    o[0] = tile[nr][kc + 0]; o[1] = tile[nr][kc + 1];
    o[2] = tile[nr][kc + 2]; o[3] = tile[nr][kc + 3];
    *(u16x4*)(Wt + (size_t)(n0 + nr) * K + k0 + kc) = o;
}

// ---------------- embedding: h f32 + hb bf16 ----------------
__global__ void embed_kernel(const int* __restrict__ ids,
                             const float* __restrict__ bpe,
                             const float* __restrict__ pos,
                             float* __restrict__ h, u16* __restrict__ hb) {
    int row = blockIdx.x;
    int s = row % SS;
    int id = ids[row];
    const float4* br = (const float4*)(bpe + (size_t)id * HH);
    const float4* pr = (const float4*)(pos + (size_t)s * HH);
    float4* hr = (float4*)(h + (size_t)row * HH);
    u16x4* hbr = (u16x4*)(hb + (size_t)row * HH);
    int t = threadIdx.x;                  // 192 threads, 1 float4 each
    float4 a = br[t], c = pr[t];
    a.x += c.x; a.y += c.y; a.z += c.z; a.w += c.w;
    hr[t] = a;
    u16x4 u; u[0] = f2bf(a.x); u[1] = f2bf(a.y); u[2] = f2bf(a.z); u[3] = f2bf(a.w);
    hbr[t] = u;
}

// ---------------- MFMA GEMM: C[M][N] = A[M][K](bf16) * Wt[N][K](bf16)^T ------
// BK=64 tiles, 2-phase double-buffer, counted vmcnt (never 0 mid-loop).
// T2 XOR-swizzle both-sides (rule #21): source k-slot pre-swizzled so linear
// global_load_lds dest + swizzled frag read are consistent.
// BM=64/128: 4 waves (256 thr). BM=256: 8 waves (512 thr), 1 block/CU.
template<int BM, int ACT, int WF32, int WBF>
__global__ __launch_bounds__(BM == 256 ? 512 : 256) void mfma_gemm(
    const u16* __restrict__ A, const u16* __restrict__ Wt,
    const float* __restrict__ bias, float* __restrict__ C,
    u16* __restrict__ Cb, int M, int N, int K) {
    constexpr int T = (BM == 256) ? 512 : 256;
    constexpr int MR = (BM >= 128) ? 4 : 2;      // M fragments per wave (span 64 or 32)
    __shared__ u16 As[2 * BM * 64];
    __shared__ u16 Bs[2 * 128 * 64];
    const int tid = threadIdx.x;
    const int lane = tid & 63;
    const int wid = tid >> 6;

    // XCD-aware bijective swizzle of flat block id
    const int nwg = gridDim.x * gridDim.y;
    int id = blockIdx.x + gridDim.x * blockIdx.y;
    int id2 = (nwg & 7) ? id : ((id & 7) * (nwg >> 3) + (id >> 3));
    const int brow = (id2 % gridDim.x) * BM;
    const int bcol = (id2 / gridDim.x) * 128;

    const int wr = (wid >> 1) * (MR * 16);
    const int wc = (wid & 1) * 64;
    f32x4 acc[MR][4] = {};

    const u16* Abase = A + (size_t)brow * K;
    const u16* Bbase = Wt + (size_t)bcol * K;
    const int lrow = lane & 15;
    const int lhi = lane >> 4;

    // stage one BK=64 tile: chunk c -> row r=c>>3, slot s=c&7; source slot s^(r&7)
    auto stage = [&](u16* Ad, u16* Bd, int kt) {
#pragma unroll
        for (int c0 = 0; c0 < BM * 8; c0 += T) {
            int c = c0 + tid;
            int r = c >> 3, s = c & 7;
            gload_lds16(Abase + (size_t)r * K + kt + ((s ^ (r & 7)) * 8), Ad + c * 8);
        }
#pragma unroll
        for (int c0 = 0; c0 < 1024; c0 += T) {
            int c = c0 + tid;
            int r = c >> 3, s = c & 7;
            gload_lds16(Bbase + (size_t)r * K + kt + ((s ^ (r & 7)) * 8), Bd + c * 8);
        }
    };

    const int nt = K / 64;
    stage(As, Bs, 0);
    for (int t = 0; t < nt; ++t) {
        u16* Ac = As + (t & 1) * (BM * 64);
        u16* Bc = Bs + (t & 1) * (128 * 64);
        if (t + 1 < nt) {
            stage(As + ((t + 1) & 1) * (BM * 64),
                  Bs + ((t + 1) & 1) * (128 * 64), (t + 1) * 64);
            if constexpr (BM == 128)      asm volatile("s_waitcnt vmcnt(8)" ::: "memory");
            else                          asm volatile("s_waitcnt vmcnt(6)" ::: "memory");
        } else {
            asm volatile("s_waitcnt vmcnt(0)" ::: "memory");
        }
        __builtin_amdgcn_s_barrier();
        __builtin_amdgcn_sched_barrier(0);

        short8 a[MR][2], b[4][2];
#pragma unroll
        for (int m = 0; m < MR; ++m) {
            const int R = wr + m * 16 + lrow;
            char* rp = (char*)Ac + R * 128;
#pragma unroll
            for (int kk = 0; kk < 2; ++kk)
                a[m][kk] = *(const short8*)(rp + (((kk * 4 + lhi) ^ (R & 7)) * 16));
        }
#pragma unroll
        for (int n = 0; n < 4; ++n) {
            const int R = wc + n * 16 + lrow;
            char* rp = (char*)Bc + R * 128;
#pragma unroll
            for (int kk = 0; kk < 2; ++kk)
                b[n][kk] = *(const short8*)(rp + (((kk * 4 + lhi) ^ (R & 7)) * 16));
        }
        __builtin_amdgcn_s_setprio(1);
#pragma unroll
        for (int kk = 0; kk < 2; ++kk)
#pragma unroll
            for (int m = 0; m < MR; ++m)
#pragma unroll
                for (int n = 0; n < 4; ++n)
                    acc[m][n] = __builtin_amdgcn_mfma_f32_16x16x32_bf16(a[m][kk], b[n][kk], acc[m][n], 0, 0, 0);
        __builtin_amdgcn_s_setprio(0);

        __builtin_amdgcn_sched_barrier(0);
        __builtin_amdgcn_s_barrier();
    }

    const int lr4 = (lane >> 4) * 4;
#pragma unroll
    for (int n = 0; n < 4; ++n) {
        int col = bcol + wc + n * 16 + lrow;
        float bv = bias ? bias[col] : 0.f;
#pragma unroll
        for (int m = 0; m < MR; ++m) {
#pragma unroll
            for (int j = 0; j < 4; ++j) {
                int row = brow + wr + m * 16 + lr4 + j;
                float v = acc[m][n][j] + bv;
                if (ACT == 1) v = 0.5f * v * (1.f + erff(v * 0.70710678118654752f));
                if (WF32) C[(size_t)row * N + col] = v;
                if (WBF)  Cb[(size_t)row * N + col] = f2bf(v);
            }
        }
    }
}

// ---------------- MFMA flash attention, split-KV=2 (flash-decode) ----------
// blockIdx.x in [0,32): qb = 15-(x>>1) (heavy-first), sp = x&1.
// Split sp owns K-tiles [kbeg,kend) of [0,qb]. Emits UNnormalized partials
// O (f32) and (m,l) per row; attn_combine merges via LSE rule.
__global__ __launch_bounds__(256) void attn_kernel(
    const u16* __restrict__ qkvb, const float* __restrict__ seq_mask,
    float* __restrict__ Opart, float2* __restrict__ ml) {
    __shared__ u16 Ks[64 * 64];
    __shared__ u16 Vt[64 * 64];
    __shared__ u16 Ps[64 * 64];
    const int qb = (gridDim.x / 2) - 1 - (blockIdx.x >> 1);   // heavy-first
    const int sp = blockIdx.x & 1;
    const int hd = blockIdx.y, b = blockIdx.z;
    const int t = threadIdx.x;
    const int lane = t & 63;
    const int w = t >> 6;
    const int lrow = lane & 15;
    const int lhi = lane >> 4;
    const int q0 = qb * 64;
    const size_t rs = 3 * HH;

    const int ntile = qb + 1;
    const int half = (ntile + 1) >> 1;
    const int kbeg = sp ? half : 0;
    const int kend = sp ? ntile : half;

    short8 aq[2];
    {
        const u16* qrow = qkvb + (size_t)(b * SS + q0 + w * 16 + lrow) * rs + hd * HDIM;
        aq[0] = *(const short8*)(qrow + lhi * 8);
        aq[1] = *(const short8*)(qrow + 32 + lhi * 8);
    }

    f32x4 o[4] = {};
    float m_[4] = {-INFINITY, -INFINITY, -INFINITY, -INFINITY};
    float l_[4] = {0.f, 0.f, 0.f, 0.f};

    const int kr = t >> 2, dc = t & 3;
    short8 kA, kB, vA, vB;
    if (kbeg < kend) {
        const u16* kbase = qkvb + (size_t)(b * SS + kbeg * 64 + kr) * rs + HH + hd * HDIM + dc * 16;
        kA = *(const short8*)(kbase);
        kB = *(const short8*)(kbase + 8);
        vA = *(const short8*)(kbase + HH);
        vB = *(const short8*)(kbase + HH + 8);
    }

    for (int kt = kbeg; kt < kend; ++kt) {
        const int k0 = kt * 64;
        __syncthreads();
        {
            char* krowp = (char*)Ks + kr * 128;
            *(short8*)(krowp + (((dc * 32 + 0)  ^ ((kr & 7) << 4)))) = kA;
            *(short8*)(krowp + (((dc * 32 + 16) ^ ((kr & 7) << 4)))) = kB;
#pragma unroll
            for (int e = 0; e < 8; ++e) {
                int d0 = dc * 16 + e;
                int d1 = dc * 16 + 8 + e;
                *(u16*)((char*)Vt + d0 * 128 + ((kr * 2) ^ ((d0 & 7) << 4))) = (u16)vA[e];
                *(u16*)((char*)Vt + d1 * 128 + ((kr * 2) ^ ((d1 & 7) << 4))) = (u16)vB[e];
            }
        }
        __syncthreads();

        if (kt + 1 < kend) {
            const u16* kbase = qkvb + (size_t)(b * SS + k0 + 64 + kr) * rs + HH + hd * HDIM + dc * 16;
            kA = *(const short8*)(kbase);
            kB = *(const short8*)(kbase + 8);
            vA = *(const short8*)(kbase + HH);
            vB = *(const short8*)(kbase + HH + 8);
        }

        f32x4 s[4] = {};
        __builtin_amdgcn_s_setprio(1);
#pragma unroll
        for (int n = 0; n < 4; ++n) {
            const int krow = n * 16 + lrow;
            char* kp = (char*)Ks + krow * 128;
#pragma unroll
            for (int c = 0; c < 2; ++c) {
                short8 bk = *(const short8*)(kp + ((c * 64 + lhi * 16) ^ ((krow & 7) << 4)));
                s[n] = __builtin_amdgcn_mfma_f32_16x16x32_bf16(aq[c], bk, s[n], 0, 0, 0);
            }
        }
        __builtin_amdgcn_s_setprio(0);

        float sm[4];
#pragma unroll
        for (int n = 0; n < 4; ++n) sm[n] = seq_mask[b * SS + k0 + n * 16 + lrow];
        const int diag = (kt == qb);
#pragma unroll
        for (int j = 0; j < 4; ++j) {
            const int qglob = q0 + w * 16 + lhi * 4 + j;
            float sv[4];
#pragma unroll
            for (int n = 0; n < 4; ++n) {
                const int kglob = k0 + n * 16 + lrow;
                float msk = (diag && kglob > qglob) ? 0.f : sm[n];
                sv[n] = s[n][j] * 0.125f + (1.f - msk) * (-1e9f);
            }
            float tm = fmaxf(fmaxf(sv[0], sv[1]), fmaxf(sv[2], sv[3]));
            tm = fmaxf(tm, __shfl_xor(tm, 1));
            tm = fmaxf(tm, __shfl_xor(tm, 2));
            tm = fmaxf(tm, __shfl_xor(tm, 4));
            tm = fmaxf(tm, __shfl_xor(tm, 8));
            float mn = fmaxf(m_[j], tm);
            float sc = __expf(m_[j] - mn);
            float ps = 0.f;
#pragma unroll
            for (int n = 0; n < 4; ++n) {
                float p = __expf(sv[n] - mn);
                s[n][j] = p;
                ps += p;
            }
            ps += __shfl_xor(ps, 1);
            ps += __shfl_xor(ps, 2);
            ps += __shfl_xor(ps, 4);
            ps += __shfl_xor(ps, 8);
            l_[j] = l_[j] * sc + ps;
            m_[j] = mn;
#pragma unroll
            for (int dn = 0; dn < 4; ++dn) o[dn][j] *= sc;
        }

#pragma unroll
        for (int j = 0; j < 4; ++j) {
            const int prow = w * 16 + lhi * 4 + j;
            char* pp = (char*)Ps + prow * 128;
#pragma unroll
            for (int n = 0; n < 4; ++n)
                *(u16*)(pp + ((n * 32 + lrow * 2) ^ ((prow & 7) << 4))) = f2bf(s[n][j]);
        }

        const int arow = w * 16 + lrow;
        char* ap_p = (char*)Ps + arow * 128;
        __builtin_amdgcn_s_setprio(1);
#pragma unroll
        for (int c = 0; c < 2; ++c) {
            short8 ap = *(const short8*)(ap_p + ((c * 64 + lhi * 16) ^ ((arow & 7) << 4)));
#pragma unroll
            for (int dn = 0; dn < 4; ++dn) {
                const int vrow = dn * 16 + lrow;
                short8 bv = *(const short8*)((char*)Vt + vrow * 128 +
                                             ((c * 64 + lhi * 16) ^ ((vrow & 7) << 4)));
                o[dn] = __builtin_amdgcn_mfma_f32_16x16x32_bf16(ap, bv, o[dn], 0, 0, 0);
            }
        }
        __builtin_amdgcn_s_setprio(0);
    }

    // ---- epilogue: write unnormalized partials ----
    float* obase = Opart + (size_t)sp * MROWS * HH;
#pragma unroll
    for (int j = 0; j < 4; ++j) {
        const int q = q0 + w * 16 + lhi * 4 + j;
        float* orow = obase + (size_t)(b * SS + q) * HH + hd * HDIM;
#pragma unroll
        for (int dn = 0; dn < 4; ++dn)
            orow[dn * 16 + lrow] = o[dn][j];
        if (lrow == 0) {
            float2 v; v.x = m_[j]; v.y = l_[j];
            ml[((size_t)sp * MROWS + b * SS + q) * NHEAD + hd] = v;
        }
    }
}

// ---------------- combine the two KV-splits (LSE merge) -> avb bf16 --------
__global__ __launch_bounds__(768) void attn_combine(
    const float* __restrict__ Opart, const float2* __restrict__ ml,
    u16* __restrict__ av) {
    const int row = blockIdx.x;           // 0..MROWS-1
    const int t = threadIdx.x;            // hd = t>>6, d = t&63
    const int hd = t >> 6;
    float2 a1 = ml[(size_t)row * NHEAD + hd];
    float2 a2 = ml[((size_t)MROWS + row) * NHEAD + hd];
    float m = fmaxf(a1.x, a2.x);
    float c1 = __expf(a1.x - m), c2 = __expf(a2.x - m);
    float inv = 1.f / (a1.y * c1 + a2.y * c2);
    float o1 = Opart[(size_t)row * HH + t];
    float o2 = Opart[(size_t)(MROWS + row) * HH + t];
    av[(size_t)row * HH + t] = f2bf((o1 * c1 + o2 * c2) * inv);
}

// ---------------- residual add + layernorm: h f32 + hb bf16 ----------------
__global__ void add_ln_kernel(float* __restrict__ h, u16* __restrict__ hb,
                              const float* __restrict__ a,
                              const float* __restrict__ g,
                              const float* __restrict__ bta) {
    int row = blockIdx.x;
    int t = threadIdx.x;
    __shared__ float red[256];
    size_t base = (size_t)row * HH;
    float x0 = h[base + t]       + a[base + t];
    float x1 = h[base + t + 256] + a[base + t + 256];
    float x2 = h[base + t + 512] + a[base + t + 512];

    red[t] = x0 + x1 + x2;
    __syncthreads();
    for (int o = 128; o; o >>= 1) { if (t < o) red[t] += red[t + o]; __syncthreads(); }
    float mean = red[0] * (1.0f / 768.0f);
    __syncthreads();

    float d0 = x0 - mean, d1 = x1 - mean, d2 = x2 - mean;
    red[t] = d0 * d0 + d1 * d1 + d2 * d2;
    __syncthreads();
    for (int o = 128; o; o >>= 1) { if (t < o) red[t] += red[t + o]; __syncthreads(); }
    float var = red[0] * (1.0f / 768.0f);
    float inv = 1.0f / sqrtf(var + 1e-5f);

    float y0 = g[t]       * d0 * inv + bta[t];
    float y1 = g[t + 256] * d1 * inv + bta[t + 256];
    float y2 = g[t + 512] * d2 * inv + bta[t + 512];
    h[base + t] = y0;       hb[base + t] = f2bf(y0);
    h[base + t + 256] = y1; hb[base + t + 256] = f2bf(y1);
    h[base + t + 512] = y2; hb[base + t + 512] = f2bf(y2);
}

// ---------------- single-pass row softmax over V=32000 ----------------
__global__ __launch_bounds__(512) void softmax_v_kernel(
    const float* __restrict__ score, float* __restrict__ prob) {
    __shared__ u16 srow[VV];        // 64000 B
    __shared__ float red[512];
    int row = blockIdx.x;
    int t = threadIdx.x;
    const float4* sr = (const float4*)(score + (size_t)row * VV);
    float4* pr = (float4*)(prob + (size_t)row * VV);
    const int n4 = VV / 4;          // 8000

    float mx = -INFINITY;
    for (int i = t; i < n4; i += 512) {
        float4 v = sr[i];
        u16x4 u; u[0] = f2bf(v.x); u[1] = f2bf(v.y); u[2] = f2bf(v.z); u[3] = f2bf(v.w);
        *(u16x4*)(srow + i * 4) = u;
        mx = fmaxf(mx, fmaxf(fmaxf(bf2f(u[0]), bf2f(u[1])), fmaxf(bf2f(u[2]), bf2f(u[3]))));
    }
    red[t] = mx; __syncthreads();
    for (int o = 256; o; o >>= 1) { if (t < o) red[t] = fmaxf(red[t], red[t + o]); __syncthreads(); }
    mx = red[0];
    __syncthreads();

    float s = 0.f;
    for (int i = t; i < n4; i += 512) {
        u16x4 u = *(const u16x4*)(srow + i * 4);
        s += __expf(bf2f(u[0]) - mx) + __expf(bf2f(u[1]) - mx)
           + __expf(bf2f(u[2]) - mx) + __expf(bf2f(u[3]) - mx);
    }
    red[t] = s; __syncthreads();
    for (int o = 256; o; o >>= 1) { if (t < o) red[t] += red[t + o]; __syncthreads(); }
    float inv = 1.0f / red[0];

    for (int i = t; i < n4; i += 512) {
        u16x4 u = *(const u16x4*)(srow + i * 4);
        float4 o4;
        o4.x = __expf(bf2f(u[0]) - mx) * inv; o4.y = __expf(bf2f(u[1]) - mx) * inv;
        o4.z = __expf(bf2f(u[2]) - mx) * inv; o4.w = __expf(bf2f(u[3]) - mx) * inv;
        pr[i] = o4;
    }
}

extern "C" void kernel_launch(void* const* d_in, const int* in_sizes, int n_in,
                              void* d_out, int out_size, void* d_ws, size_t ws_size,
                              hipStream_t stream) {
    const int*   ids      = (const int*)d_in[0];
    const float* seq_mask = (const float*)d_in[1];
    const float* bpe      = (const float*)d_in[2];
    const float* pos      = (const float*)d_in[3];
    const float* qkv_w    = (const float*)d_in[4];
    const float* qkv_b    = (const float*)d_in[5];
    const float* res_w    = (const float*)d_in[6];
    const float* res_b    = (const float*)d_in[7];
    const float* ln1_g    = (const float*)d_in[8];
    const float* ln1_b    = (const float*)d_in[9];
    const float* ff1_w    = (const float*)d_in[10];
    const float* ff1_b    = (const float*)d_in[11];
    const float* ff2_w    = (const float*)d_in[12];
    const float* ff2_b    = (const float*)d_in[13];
    const float* ln2_g    = (const float*)d_in[14];
    const float* ln2_b    = (const float*)d_in[15];
    const float* pred_w   = (const float*)d_in[16];

    float* out_score = (float*)d_out;
    float* out_prob  = out_score + (size_t)MROWS * VV;

    // arena layout
    size_t off = 0;
    auto take = [&](size_t bytes) -> size_t {
        size_t p = off; off += (bytes + 255) & ~(size_t)255; return p;
    };
    const size_t o_qkvT = take((size_t)NLAYER * HH * 3 * HH * 2);
    const size_t o_resT = take((size_t)NLAYER * HH * HH * 2);
    const size_t o_ff1T = take((size_t)NLAYER * HH * 4 * HH * 2);
    const size_t o_ff2T = take((size_t)NLAYER * 4 * HH * HH * 2);
    const size_t o_predT = take((size_t)HH * VV * 2);
    const size_t o_h    = take((size_t)MROWS * HH * 4);
    const size_t o_a    = take((size_t)MROWS * HH * 4);
    const size_t o_qkvb = take((size_t)MROWS * 3 * HH * 2);
    const size_t o_hb   = take((size_t)MROWS * HH * 2);
    const size_t o_avb  = take((size_t)MROWS * HH * 2);
    const size_t o_midb = take((size_t)MROWS * 4 * HH * 2);
    const size_t o_op   = take((size_t)2 * MROWS * HH * 4);
    const size_t o_ml   = take((size_t)2 * MROWS * NHEAD * 8);
    const size_t need = off;

    char* arena = (ws_size >= need) ? (char*)d_ws : (char*)out_prob;
    u16*   qkvT = (u16*)(arena + o_qkvT);
    u16*   resT = (u16*)(arena + o_resT);
    u16*   ff1T = (u16*)(arena + o_ff1T);
    u16*   ff2T = (u16*)(arena + o_ff2T);
    u16*   predT = (u16*)(arena + o_predT);
    float* h    = (float*)(arena + o_h);
    float* a    = (float*)(arena + o_a);
    u16*   qkvb = (u16*)(arena + o_qkvb);
    u16*   hb   = (u16*)(arena + o_hb);
    u16*   avb  = (u16*)(arena + o_avb);
    u16*   midb = (u16*)(arena + o_midb);
    float* opart = (float*)(arena + o_op);
    float2* mlb  = (float2*)(arena + o_ml);

    conv_transpose<<<dim3(3 * HH / 32, HH / 32, NLAYER), 256, 0, stream>>>(qkv_w, qkvT, HH, 3 * HH);
    conv_transpose<<<dim3(HH / 32, HH / 32, NLAYER), 256, 0, stream>>>(res_w, resT, HH, HH);
    conv_transpose<<<dim3(4 * HH / 32, HH / 32, NLAYER), 256, 0, stream>>>(ff1_w, ff1T, HH, 4 * HH);
    conv_transpose<<<dim3(HH / 32, 4 * HH / 32, NLAYER), 256, 0, stream>>>(ff2_w, ff2T, 4 * HH, HH);
    conv_transpose<<<dim3(VV / 32, HH / 32, 1), 256, 0, stream>>>(pred_w, predT, HH, VV);

    embed_kernel<<<MROWS, 192, 0, stream>>>(ids, bpe, pos, h, hb);

    for (int l = 0; l < NLAYER; ++l) {
        mfma_gemm<128, 0, 0, 1><<<dim3(MROWS / 128, 3 * HH / 128), 256, 0, stream>>>(
            hb, qkvT + (size_t)l * HH * 3 * HH, qkv_b + (size_t)l * 3 * HH,
            nullptr, qkvb, MROWS, 3 * HH, HH);
        attn_kernel<<<dim3(SS / 64 * 2, NHEAD, BB), 256, 0, stream>>>(qkvb, seq_mask, opart, mlb);
        attn_combine<<<MROWS, 768, 0, stream>>>(opart, mlb, avb);
        mfma_gemm<64, 0, 1, 0><<<dim3(MROWS / 64, HH / 128), 256, 0, stream>>>(
            avb, resT + (size_t)l * HH * HH, res_b + (size_t)l * HH,
            a, nullptr, MROWS, HH, HH);
        add_ln_kernel<<<MROWS, 256, 0, stream>>>(h, hb, a,
            ln1_g + (size_t)l * HH, ln1_b + (size_t)l * HH);
        mfma_gemm<128, 1, 0, 1><<<dim3(MROWS / 128, 4 * HH / 128), 256, 0, stream>>>(
            hb, ff1T + (size_t)l * HH * 4 * HH, ff1_b + (size_t)l * 4 * HH,
            nullptr, midb, MROWS, 4 * HH, HH);
        mfma_gemm<64, 0, 1, 0><<<dim3(MROWS / 64, HH / 128), 256, 0, stream>>>(
            midb, ff2T + (size_t)l * 4 * HH * HH, ff2_b + (size_t)l * HH,
            a, nullptr, MROWS, HH, 4 * HH);
        add_ln_kernel<<<MROWS, 256, 0, stream>>>(h, hb, a,
            ln2_g + (size_t)l * HH, ln2_b + (size_t)l * HH);
    }

    mfma_gemm<256, 0, 1, 0><<<dim3(MROWS / 256, VV / 128), 512, 0, stream>>>(
        hb, predT, nullptr, out_score, nullptr, MROWS, VV, HH);
    softmax_v_kernel<<<MROWS, 512, 0, stream>>>(out_score, out_prob);
}

// Round 10
// 1011.746 us; speedup vs baseline: 1.0336x; 1.0336x over previous
//
#include <hip/hip_runtime.h>
#include <math.h>

#define BB 2
#define SS 1024
#define HH 768
#define NHEAD 12
#define HDIM 64
#define NLAYER 4
#define VV 32000
#define MROWS (BB*SS)

typedef unsigned short u16;
typedef __attribute__((ext_vector_type(8))) short short8;
typedef __attribute__((ext_vector_type(4))) float f32x4;
typedef __attribute__((ext_vector_type(4))) unsigned short u16x4;

__device__ __forceinline__ u16 f2bf(float f) {
    union { float f; unsigned u; } x; x.f = f;
    unsigned r = (x.u + 0x7fff + ((x.u >> 16) & 1)) >> 16;
    return (u16)r;
}
__device__ __forceinline__ float bf2f(u16 b) {
    union { unsigned u; float f; } x; x.u = ((unsigned)b) << 16;
    return x.f;
}

__device__ __forceinline__ void gload_lds16(const u16* g, u16* l) {
    __builtin_amdgcn_global_load_lds((const __attribute__((address_space(1))) void*)g,
                                     (__attribute__((address_space(3))) void*)l, 16, 0, 0);
}

// ---------------- weight convert + transpose: W[K][N] f32 -> Wt[N][K] bf16 ----
__global__ __launch_bounds__(256) void conv_transpose(
    const float* __restrict__ W, u16* __restrict__ Wt, int K, int N) {
    int l = blockIdx.z;
    W  += (size_t)l * K * N;
    Wt += (size_t)l * K * N;
    __shared__ u16 tile[32][33];        // tile[n][k]
    int k0 = blockIdx.y * 32, n0 = blockIdx.x * 32;
    int t = threadIdx.x;                // 256
    int ky = t >> 3, nx = (t & 7) * 4;  // load: row k0+ky, cols n0+nx..+3
    float4 v = *(const float4*)(W + (size_t)(k0 + ky) * N + n0 + nx);
    tile[nx + 0][ky] = f2bf(v.x);
    tile[nx + 1][ky] = f2bf(v.y);
    tile[nx + 2][ky] = f2bf(v.z);
    tile[nx + 3][ky] = f2bf(v.w);
    __syncthreads();
    int nr = t >> 3, kc = (t & 7) * 4;  // store: row n0+nr, cols k0+kc..+3
    u16x4 o;
    o[0] = tile[nr][kc + 0]; o[1] = tile[nr][kc + 1];
    o[2] = tile[nr][kc + 2]; o[3] = tile[nr][kc + 3];
    *(u16x4*)(Wt + (size_t)(n0 + nr) * K + k0 + kc) = o;
}

// ---------------- embedding: h f32 + hb bf16 ----------------
__global__ void embed_kernel(const int* __restrict__ ids,
                             const float* __restrict__ bpe,
                             const float* __restrict__ pos,
                             float* __restrict__ h, u16* __restrict__ hb) {
    int row = blockIdx.x;
    int s = row % SS;
    int id = ids[row];
    const float4* br = (const float4*)(bpe + (size_t)id * HH);
    const float4* pr = (const float4*)(pos + (size_t)s * HH);
    float4* hr = (float4*)(h + (size_t)row * HH);
    u16x4* hbr = (u16x4*)(hb + (size_t)row * HH);
    int t = threadIdx.x;                  // 192 threads, 1 float4 each
    float4 a = br[t], c = pr[t];
    a.x += c.x; a.y += c.y; a.z += c.z; a.w += c.w;
    hr[t] = a;
    u16x4 u; u[0] = f2bf(a.x); u[1] = f2bf(a.y); u[2] = f2bf(a.z); u[3] = f2bf(a.w);
    hbr[t] = u;
}

// ---------------- MFMA GEMM: C[M][N] = A[M][K](bf16) * Wt[N][K](bf16)^T ------
// BK=64 tiles, 2-phase double-buffer, counted vmcnt (never 0 mid-loop).
// T2 XOR-swizzle both-sides (rule #21): source k-slot pre-swizzled so linear
// global_load_lds dest + swizzled frag read are consistent.
// BM=64 for narrow/imbalanced grids (3 blocks/CU), BM=128 for wide ones.
template<int BM, int ACT, int WF32, int WBF>
__global__ __launch_bounds__(256) void mfma_gemm(
    const u16* __restrict__ A, const u16* __restrict__ Wt,
    const float* __restrict__ bias, float* __restrict__ C,
    u16* __restrict__ Cb, int M, int N, int K) {
    constexpr int MR = (BM >= 128) ? 4 : 2;      // M fragments per wave
    __shared__ u16 As[2 * BM * 64];
    __shared__ u16 Bs[2 * 128 * 64];
    const int tid = threadIdx.x;
    const int lane = tid & 63;
    const int wid = tid >> 6;

    // XCD-aware bijective swizzle of flat block id
    const int nwg = gridDim.x * gridDim.y;
    int id = blockIdx.x + gridDim.x * blockIdx.y;
    int id2 = (nwg & 7) ? id : ((id & 7) * (nwg >> 3) + (id >> 3));
    const int brow = (id2 % gridDim.x) * BM;
    const int bcol = (id2 / gridDim.x) * 128;

    const int wr = (wid >> 1) * (MR * 16);
    const int wc = (wid & 1) * 64;
    f32x4 acc[MR][4] = {};

    const u16* Abase = A + (size_t)brow * K;
    const u16* Bbase = Wt + (size_t)bcol * K;
    const int lrow = lane & 15;
    const int lhi = lane >> 4;

    // stage one BK=64 tile: chunk c -> row r=c>>3, slot s=c&7; source slot s^(r&7)
    auto stage = [&](u16* Ad, u16* Bd, int kt) {
#pragma unroll
        for (int c0 = 0; c0 < BM * 8; c0 += 256) {
            int c = c0 + tid;
            int r = c >> 3, s = c & 7;
            gload_lds16(Abase + (size_t)r * K + kt + ((s ^ (r & 7)) * 8), Ad + c * 8);
        }
#pragma unroll
        for (int c0 = 0; c0 < 1024; c0 += 256) {
            int c = c0 + tid;
            int r = c >> 3, s = c & 7;
            gload_lds16(Bbase + (size_t)r * K + kt + ((s ^ (r & 7)) * 8), Bd + c * 8);
        }
    };

    const int nt = K / 64;
    stage(As, Bs, 0);
    for (int t = 0; t < nt; ++t) {
        u16* Ac = As + (t & 1) * (BM * 64);
        u16* Bc = Bs + (t & 1) * (128 * 64);
        if (t + 1 < nt) {
            stage(As + ((t + 1) & 1) * (BM * 64),
                  Bs + ((t + 1) & 1) * (128 * 64), (t + 1) * 64);
            if constexpr (BM == 128)      asm volatile("s_waitcnt vmcnt(8)" ::: "memory");
            else                          asm volatile("s_waitcnt vmcnt(6)" ::: "memory");
        } else {
            asm volatile("s_waitcnt vmcnt(0)" ::: "memory");
        }
        __builtin_amdgcn_s_barrier();
        __builtin_amdgcn_sched_barrier(0);

        short8 a[MR][2], b[4][2];
#pragma unroll
        for (int m = 0; m < MR; ++m) {
            const int R = wr + m * 16 + lrow;
            char* rp = (char*)Ac + R * 128;
#pragma unroll
            for (int kk = 0; kk < 2; ++kk)
                a[m][kk] = *(const short8*)(rp + (((kk * 4 + lhi) ^ (R & 7)) * 16));
        }
#pragma unroll
        for (int n = 0; n < 4; ++n) {
            const int R = wc + n * 16 + lrow;
            char* rp = (char*)Bc + R * 128;
#pragma unroll
            for (int kk = 0; kk < 2; ++kk)
                b[n][kk] = *(const short8*)(rp + (((kk * 4 + lhi) ^ (R & 7)) * 16));
        }
        __builtin_amdgcn_s_setprio(1);
#pragma unroll
        for (int kk = 0; kk < 2; ++kk)
#pragma unroll
            for (int m = 0; m < MR; ++m)
#pragma unroll
                for (int n = 0; n < 4; ++n)
                    acc[m][n] = __builtin_amdgcn_mfma_f32_16x16x32_bf16(a[m][kk], b[n][kk], acc[m][n], 0, 0, 0);
        __builtin_amdgcn_s_setprio(0);

        __builtin_amdgcn_sched_barrier(0);
        __builtin_amdgcn_s_barrier();
    }

    const int lr4 = (lane >> 4) * 4;
#pragma unroll
    for (int n = 0; n < 4; ++n) {
        int col = bcol + wc + n * 16 + lrow;
        float bv = bias ? bias[col] : 0.f;
#pragma unroll
        for (int m = 0; m < MR; ++m) {
#pragma unroll
            for (int j = 0; j < 4; ++j) {
                int row = brow + wr + m * 16 + lr4 + j;
                float v = acc[m][n][j] + bv;
                if (ACT == 1) v = 0.5f * v * (1.f + erff(v * 0.70710678118654752f));
                if (WF32) C[(size_t)row * N + col] = v;
                if (WBF)  Cb[(size_t)row * N + col] = f2bf(v);
            }
        }
    }
}

// ---------------- MFMA flash attention (bf16 QKV input) ----------------
// block = 64 q-rows of one (b,head); 4 waves; wave w owns q-rows [16w,16w+16).
// K tile [k][d] and V^T tile [d][k] bf16 in LDS, XOR-swizzled (byte^=(row&7)<<4).
// Reg-prefetch of next K/V tile overlaps global latency with compute (T14);
// heavy blocks (large qb) dispatched first.
__global__ __launch_bounds__(256) void attn_kernel(
    const u16* __restrict__ qkvb, const float* __restrict__ seq_mask,
    u16* __restrict__ av) {
    __shared__ u16 Ks[64 * 64];
    __shared__ u16 Vt[64 * 64];
    __shared__ u16 Ps[64 * 64];
    const int qb = gridDim.x - 1 - blockIdx.x;   // heavy-first
    const int hd = blockIdx.y, b = blockIdx.z;
    const int t = threadIdx.x;
    const int lane = t & 63;
    const int w = t >> 6;
    const int lrow = lane & 15;
    const int lhi = lane >> 4;
    const int q0 = qb * 64;
    const size_t rs = 3 * HH;

    short8 aq[2];
    {
        const u16* qrow = qkvb + (size_t)(b * SS + q0 + w * 16 + lrow) * rs + hd * HDIM;
        aq[0] = *(const short8*)(qrow + lhi * 8);
        aq[1] = *(const short8*)(qrow + 32 + lhi * 8);
    }

    f32x4 o[4] = {};
    float m_[4] = {-INFINITY, -INFINITY, -INFINITY, -INFINITY};
    float l_[4] = {0.f, 0.f, 0.f, 0.f};

    const int kr = t >> 2, dc = t & 3;
    short8 kA, kB, vA, vB;
    {
        const u16* kbase = qkvb + (size_t)(b * SS + kr) * rs + HH + hd * HDIM + dc * 16;
        kA = *(const short8*)(kbase);
        kB = *(const short8*)(kbase + 8);
        vA = *(const short8*)(kbase + HH);
        vB = *(const short8*)(kbase + HH + 8);
    }

    for (int kt = 0; kt <= qb; ++kt) {
        const int k0 = kt * 64;
        __syncthreads();
        {
            char* krowp = (char*)Ks + kr * 128;
            *(short8*)(krowp + (((dc * 32 + 0)  ^ ((kr & 7) << 4)))) = kA;
            *(short8*)(krowp + (((dc * 32 + 16) ^ ((kr & 7) << 4)))) = kB;
#pragma unroll
            for (int e = 0; e < 8; ++e) {
                int d0 = dc * 16 + e;
                int d1 = dc * 16 + 8 + e;
                *(u16*)((char*)Vt + d0 * 128 + ((kr * 2) ^ ((d0 & 7) << 4))) = (u16)vA[e];
                *(u16*)((char*)Vt + d1 * 128 + ((kr * 2) ^ ((d1 & 7) << 4))) = (u16)vB[e];
            }
        }
        __syncthreads();

        if (kt < qb) {
            const u16* kbase = qkvb + (size_t)(b * SS + k0 + 64 + kr) * rs + HH + hd * HDIM + dc * 16;
            kA = *(const short8*)(kbase);
            kB = *(const short8*)(kbase + 8);
            vA = *(const short8*)(kbase + HH);
            vB = *(const short8*)(kbase + HH + 8);
        }

        f32x4 s[4] = {};
        __builtin_amdgcn_s_setprio(1);
#pragma unroll
        for (int n = 0; n < 4; ++n) {
            const int krow = n * 16 + lrow;
            char* kp = (char*)Ks + krow * 128;
#pragma unroll
            for (int c = 0; c < 2; ++c) {
                short8 bk = *(const short8*)(kp + ((c * 64 + lhi * 16) ^ ((krow & 7) << 4)));
                s[n] = __builtin_amdgcn_mfma_f32_16x16x32_bf16(aq[c], bk, s[n], 0, 0, 0);
            }
        }
        __builtin_amdgcn_s_setprio(0);

        float sm[4];
#pragma unroll
        for (int n = 0; n < 4; ++n) sm[n] = seq_mask[b * SS + k0 + n * 16 + lrow];
        const int diag = (kt == qb);
#pragma unroll
        for (int j = 0; j < 4; ++j) {
            const int qglob = q0 + w * 16 + lhi * 4 + j;
            float sv[4];
#pragma unroll
            for (int n = 0; n < 4; ++n) {
                const int kglob = k0 + n * 16 + lrow;
                float msk = (diag && kglob > qglob) ? 0.f : sm[n];
                sv[n] = s[n][j] * 0.125f + (1.f - msk) * (-1e9f);
            }
            float tm = fmaxf(fmaxf(sv[0], sv[1]), fmaxf(sv[2], sv[3]));
            tm = fmaxf(tm, __shfl_xor(tm, 1));
            tm = fmaxf(tm, __shfl_xor(tm, 2));
            tm = fmaxf(tm, __shfl_xor(tm, 4));
            tm = fmaxf(tm, __shfl_xor(tm, 8));
            float mn = fmaxf(m_[j], tm);
            float sc = __expf(m_[j] - mn);
            float ps = 0.f;
#pragma unroll
            for (int n = 0; n < 4; ++n) {
                float p = __expf(sv[n] - mn);
                s[n][j] = p;
                ps += p;
            }
            ps += __shfl_xor(ps, 1);
            ps += __shfl_xor(ps, 2);
            ps += __shfl_xor(ps, 4);
            ps += __shfl_xor(ps, 8);
            l_[j] = l_[j] * sc + ps;
            m_[j] = mn;
#pragma unroll
            for (int dn = 0; dn < 4; ++dn) o[dn][j] *= sc;
        }

#pragma unroll
        for (int j = 0; j < 4; ++j) {
            const int prow = w * 16 + lhi * 4 + j;
            char* pp = (char*)Ps + prow * 128;
#pragma unroll
            for (int n = 0; n < 4; ++n)
                *(u16*)(pp + ((n * 32 + lrow * 2) ^ ((prow & 7) << 4))) = f2bf(s[n][j]);
        }

        const int arow = w * 16 + lrow;
        char* ap_p = (char*)Ps + arow * 128;
        __builtin_amdgcn_s_setprio(1);
#pragma unroll
        for (int c = 0; c < 2; ++c) {
            short8 ap = *(const short8*)(ap_p + ((c * 64 + lhi * 16) ^ ((arow & 7) << 4)));
#pragma unroll
            for (int dn = 0; dn < 4; ++dn) {
                const int vrow = dn * 16 + lrow;
                short8 bv = *(const short8*)((char*)Vt + vrow * 128 +
                                             ((c * 64 + lhi * 16) ^ ((vrow & 7) << 4)));
                o[dn] = __builtin_amdgcn_mfma_f32_16x16x32_bf16(ap, bv, o[dn], 0, 0, 0);
            }
        }
        __builtin_amdgcn_s_setprio(0);
    }

#pragma unroll
    for (int j = 0; j < 4; ++j) {
        const int q = q0 + w * 16 + lhi * 4 + j;
        const float inv = 1.f / l_[j];
        u16* orow = av + (size_t)(b * SS + q) * HH + hd * HDIM;
#pragma unroll
        for (int dn = 0; dn < 4; ++dn)
            orow[dn * 16 + lrow] = f2bf(o[dn][j] * inv);
    }
}

// ---------------- residual add + layernorm: h f32 + hb bf16 ----------------
__global__ void add_ln_kernel(float* __restrict__ h, u16* __restrict__ hb,
                              const float* __restrict__ a,
                              const float* __restrict__ g,
                              const float* __restrict__ bta) {
    int row = blockIdx.x;
    int t = threadIdx.x;
    __shared__ float red[256];
    size_t base = (size_t)row * HH;
    float x0 = h[base + t]       + a[base + t];
    float x1 = h[base + t + 256] + a[base + t + 256];
    float x2 = h[base + t + 512] + a[base + t + 512];

    red[t] = x0 + x1 + x2;
    __syncthreads();
    for (int o = 128; o; o >>= 1) { if (t < o) red[t] += red[t + o]; __syncthreads(); }
    float mean = red[0] * (1.0f / 768.0f);
    __syncthreads();

    float d0 = x0 - mean, d1 = x1 - mean, d2 = x2 - mean;
    red[t] = d0 * d0 + d1 * d1 + d2 * d2;
    __syncthreads();
    for (int o = 128; o; o >>= 1) { if (t < o) red[t] += red[t + o]; __syncthreads(); }
    float var = red[0] * (1.0f / 768.0f);
    float inv = 1.0f / sqrtf(var + 1e-5f);

    float y0 = g[t]       * d0 * inv + bta[t];
    float y1 = g[t + 256] * d1 * inv + bta[t + 256];
    float y2 = g[t + 512] * d2 * inv + bta[t + 512];
    h[base + t] = y0;       hb[base + t] = f2bf(y0);
    h[base + t + 256] = y1; hb[base + t + 256] = f2bf(y1);
    h[base + t + 512] = y2; hb[base + t + 512] = f2bf(y2);
}

// ---------------- single-pass row softmax over V=32000 ----------------
__global__ __launch_bounds__(512) void softmax_v_kernel(
    const float* __restrict__ score, float* __restrict__ prob) {
    __shared__ u16 srow[VV];        // 64000 B
    __shared__ float red[512];
    int row = blockIdx.x;
    int t = threadIdx.x;
    const float4* sr = (const float4*)(score + (size_t)row * VV);
    float4* pr = (float4*)(prob + (size_t)row * VV);
    const int n4 = VV / 4;          // 8000

    float mx = -INFINITY;
    for (int i = t; i < n4; i += 512) {
        float4 v = sr[i];
        u16x4 u; u[0] = f2bf(v.x); u[1] = f2bf(v.y); u[2] = f2bf(v.z); u[3] = f2bf(v.w);
        *(u16x4*)(srow + i * 4) = u;
        mx = fmaxf(mx, fmaxf(fmaxf(bf2f(u[0]), bf2f(u[1])), fmaxf(bf2f(u[2]), bf2f(u[3]))));
    }
    red[t] = mx; __syncthreads();
    for (int o = 256; o; o >>= 1) { if (t < o) red[t] = fmaxf(red[t], red[t + o]); __syncthreads(); }
    mx = red[0];
    __syncthreads();

    float s = 0.f;
    for (int i = t; i < n4; i += 512) {
        u16x4 u = *(const u16x4*)(srow + i * 4);
        s += __expf(bf2f(u[0]) - mx) + __expf(bf2f(u[1]) - mx)
           + __expf(bf2f(u[2]) - mx) + __expf(bf2f(u[3]) - mx);
    }
    red[t] = s; __syncthreads();
    for (int o = 256; o; o >>= 1) { if (t < o) red[t] += red[t + o]; __syncthreads(); }
    float inv = 1.0f / red[0];

    for (int i = t; i < n4; i += 512) {
        u16x4 u = *(const u16x4*)(srow + i * 4);
        float4 o4;
        o4.x = __expf(bf2f(u[0]) - mx) * inv; o4.y = __expf(bf2f(u[1]) - mx) * inv;
        o4.z = __expf(bf2f(u[2]) - mx) * inv; o4.w = __expf(bf2f(u[3]) - mx) * inv;
        pr[i] = o4;
    }
}

extern "C" void kernel_launch(void* const* d_in, const int* in_sizes, int n_in,
                              void* d_out, int out_size, void* d_ws, size_t ws_size,
                              hipStream_t stream) {
    const int*   ids      = (const int*)d_in[0];
    const float* seq_mask = (const float*)d_in[1];
    const float* bpe      = (const float*)d_in[2];
    const float* pos      = (const float*)d_in[3];
    const float* qkv_w    = (const float*)d_in[4];
    const float* qkv_b    = (const float*)d_in[5];
    const float* res_w    = (const float*)d_in[6];
    const float* res_b    = (const float*)d_in[7];
    const float* ln1_g    = (const float*)d_in[8];
    const float* ln1_b    = (const float*)d_in[9];
    const float* ff1_w    = (const float*)d_in[10];
    const float* ff1_b    = (const float*)d_in[11];
    const float* ff2_w    = (const float*)d_in[12];
    const float* ff2_b    = (const float*)d_in[13];
    const float* ln2_g    = (const float*)d_in[14];
    const float* ln2_b    = (const float*)d_in[15];
    const float* pred_w   = (const float*)d_in[16];

    float* out_score = (float*)d_out;
    float* out_prob  = out_score + (size_t)MROWS * VV;

    // arena layout
    size_t off = 0;
    auto take = [&](size_t bytes) -> size_t {
        size_t p = off; off += (bytes + 255) & ~(size_t)255; return p;
    };
    const size_t o_qkvT = take((size_t)NLAYER * HH * 3 * HH * 2);
    const size_t o_resT = take((size_t)NLAYER * HH * HH * 2);
    const size_t o_ff1T = take((size_t)NLAYER * HH * 4 * HH * 2);
    const size_t o_ff2T = take((size_t)NLAYER * 4 * HH * HH * 2);
    const size_t o_predT = take((size_t)HH * VV * 2);
    const size_t o_h    = take((size_t)MROWS * HH * 4);
    const size_t o_a    = take((size_t)MROWS * HH * 4);
    const size_t o_qkvb = take((size_t)MROWS * 3 * HH * 2);
    const size_t o_hb   = take((size_t)MROWS * HH * 2);
    const size_t o_avb  = take((size_t)MROWS * HH * 2);
    const size_t o_midb = take((size_t)MROWS * 4 * HH * 2);
    const size_t need = off;

    char* arena = (ws_size >= need) ? (char*)d_ws : (char*)out_prob;
    u16*   qkvT = (u16*)(arena + o_qkvT);
    u16*   resT = (u16*)(arena + o_resT);
    u16*   ff1T = (u16*)(arena + o_ff1T);
    u16*   ff2T = (u16*)(arena + o_ff2T);
    u16*   predT = (u16*)(arena + o_predT);
    float* h    = (float*)(arena + o_h);
    float* a    = (float*)(arena + o_a);
    u16*   qkvb = (u16*)(arena + o_qkvb);
    u16*   hb   = (u16*)(arena + o_hb);
    u16*   avb  = (u16*)(arena + o_avb);
    u16*   midb = (u16*)(arena + o_midb);

    conv_transpose<<<dim3(3 * HH / 32, HH / 32, NLAYER), 256, 0, stream>>>(qkv_w, qkvT, HH, 3 * HH);
    conv_transpose<<<dim3(HH / 32, HH / 32, NLAYER), 256, 0, stream>>>(res_w, resT, HH, HH);
    conv_transpose<<<dim3(4 * HH / 32, HH / 32, NLAYER), 256, 0, stream>>>(ff1_w, ff1T, HH, 4 * HH);
    conv_transpose<<<dim3(HH / 32, 4 * HH / 32, NLAYER), 256, 0, stream>>>(ff2_w, ff2T, 4 * HH, HH);
    conv_transpose<<<dim3(VV / 32, HH / 32, 1), 256, 0, stream>>>(pred_w, predT, HH, VV);

    embed_kernel<<<MROWS, 192, 0, stream>>>(ids, bpe, pos, h, hb);

    for (int l = 0; l < NLAYER; ++l) {
        mfma_gemm<64, 0, 0, 1><<<dim3(MROWS / 64, 3 * HH / 128), 256, 0, stream>>>(
            hb, qkvT + (size_t)l * HH * 3 * HH, qkv_b + (size_t)l * 3 * HH,
            nullptr, qkvb, MROWS, 3 * HH, HH);
        attn_kernel<<<dim3(SS / 64, NHEAD, BB), 256, 0, stream>>>(qkvb, seq_mask, avb);
        mfma_gemm<64, 0, 1, 0><<<dim3(MROWS / 64, HH / 128), 256, 0, stream>>>(
            avb, resT + (size_t)l * HH * HH, res_b + (size_t)l * HH,
            a, nullptr, MROWS, HH, HH);
        add_ln_kernel<<<MROWS, 256, 0, stream>>>(h, hb, a,
            ln1_g + (size_t)l * HH, ln1_b + (size_t)l * HH);
        mfma_gemm<64, 1, 0, 1><<<dim3(MROWS / 64, 4 * HH / 128), 256, 0, stream>>>(
            hb, ff1T + (size_t)l * HH * 4 * HH, ff1_b + (size_t)l * 4 * HH,
            nullptr, midb, MROWS, 4 * HH, HH);
        mfma_gemm<64, 0, 1, 0><<<dim3(MROWS / 64, HH / 128), 256, 0, stream>>>(
            midb, ff2T + (size_t)l * 4 * HH * HH, ff2_b + (size_t)l * HH,
            a, nullptr, MROWS, HH, 4 * HH);
        add_ln_kernel<<<MROWS, 256, 0, stream>>>(h, hb, a,
            ln2_g + (size_t)l * HH, ln2_b + (size_t)l * HH);
    }

    mfma_gemm<128, 0, 1, 0><<<dim3(MROWS / 128, VV / 128), 256, 0, stream>>>(
        hb, predT, nullptr, out_score, nullptr, MROWS, VV, HH);
    softmax_v_kernel<<<MROWS, 512, 0, stream>>>(out_score, out_prob);
}